// Round 1
// baseline (18036.143 us; speedup 1.0000x reference)
//
#include <hip/hip_runtime.h>
#include <hip/hip_cooperative_groups.h>

namespace cg = cooperative_groups;

// ---------------------------------------------------------------------------
// LSTM: B=64, SEQ=512, I=1024, H=1024, O=512, fp32 in/out.
// Plan:
//   prep:   pack Wh4/Wx4 -> bf16 [4096][1024], bias[n]=b_h+b_x, X->bf16,
//           hT0[b][k] = h0[k] (bf16), wT[k][o] = w[o][k] (fp32)
//   phase1: Xg[t][n][b] = X[b,t,:] . Wx4[n,:] + bias[n]   (bf16 MFMA GEMM)
//   phase2: cooperative persistent kernel, 512 steps, Wh A-frags in VGPRs,
//           h slice staged in LDS, c in thread registers, 1 grid.sync/step
//   out:    out[b][o] = h[b,:] . w[o,:]
// ---------------------------------------------------------------------------

typedef short short8 __attribute__((ext_vector_type(8)));   // 8 bf16 (guide-verified frag type)
typedef float f32x4 __attribute__((ext_vector_type(4)));

#define HID   1024
#define G4    4096
#define NBAT  64
#define SEQL  512
#define OUTD  512

__device__ __forceinline__ unsigned short f2bf(float f) {
    unsigned int u = __builtin_bit_cast(unsigned int, f);
    u += 0x7FFFu + ((u >> 16) & 1u);            // round-to-nearest-even
    return (unsigned short)(u >> 16);
}
__device__ __forceinline__ float bf2f(unsigned short s) {
    unsigned int u = ((unsigned int)s) << 16;
    return __builtin_bit_cast(float, u);
}
__device__ __forceinline__ float sigmoidf_fast(float x) {
    return 1.f / (1.f + __expf(-x));
}
__device__ __forceinline__ float tanhf_fast(float x) {
    // 1 - 2/(exp(2x)+1): safe at +/-inf of exp
    return 1.f - 2.f / (1.f + __expf(2.f * x));
}

// --- prep: pack 4 gate weight matrices (fp32 [1024][1024] each) into bf16 [4096][1024]
__global__ void k_pack_w(const float* __restrict__ w0, const float* __restrict__ w1,
                         const float* __restrict__ w2, const float* __restrict__ w3,
                         unsigned short* __restrict__ dst) {
    int idx4 = blockIdx.x * blockDim.x + threadIdx.x;   // over 4096*1024/4 = 1048576
    int n  = idx4 >> 8;            // row 0..4095  (256 float4 per row)
    int k4 = (idx4 & 255) * 4;
    int g = n >> 10, r = n & 1023;
    const float* src = (g == 0) ? w0 : (g == 1) ? w1 : (g == 2) ? w2 : w3;
    float4 v = *(const float4*)(src + r * 1024 + k4);
    ushort4 o;
    o.x = f2bf(v.x); o.y = f2bf(v.y); o.z = f2bf(v.z); o.w = f2bf(v.w);
    *(ushort4*)(dst + n * 1024 + k4) = o;
}

// --- prep: bias[4096], hT0 (bf16 [64][1024] = h0 broadcast), wT (fp32 [1024][512])
__global__ void k_misc(const float* __restrict__ b_hi, const float* __restrict__ b_xi,
                       const float* __restrict__ b_hf, const float* __restrict__ b_xf,
                       const float* __restrict__ b_ho, const float* __restrict__ b_xo,
                       const float* __restrict__ b_hg, const float* __restrict__ b_xg,
                       const float* __restrict__ h0, const float* __restrict__ w,
                       float* __restrict__ bias, unsigned short* __restrict__ hT0,
                       float* __restrict__ wT) {
    int idx = blockIdx.x * blockDim.x + threadIdx.x;
    if (idx < 4096) {
        int g = idx >> 10, r = idx & 1023;
        const float* bh = (g == 0) ? b_hi : (g == 1) ? b_hf : (g == 2) ? b_ho : b_hg;
        const float* bx = (g == 0) ? b_xi : (g == 1) ? b_xf : (g == 2) ? b_xo : b_xg;
        bias[idx] = bh[r] + bx[r];
    } else if (idx < 4096 + 65536) {
        int e = idx - 4096;
        int k = e & 1023;
        hT0[e] = f2bf(h0[k]);
    } else if (idx < 4096 + 65536 + 524288) {
        int e = idx - 69632;
        int k = e >> 9, o = e & 511;
        wT[e] = w[o * 1024 + k];
    }
}

// --- prep: X fp32 -> bf16, same (b,t,k) layout
__global__ void k_convert_x(const float* __restrict__ X, unsigned short* __restrict__ Xb) {
    int idx = blockIdx.x * blockDim.x + threadIdx.x;    // over 33554432/4
    float4 v = ((const float4*)X)[idx];
    ushort4 o;
    o.x = f2bf(v.x); o.y = f2bf(v.y); o.z = f2bf(v.z); o.w = f2bf(v.w);
    ((ushort4*)Xb)[idx] = o;
}

// --- phase 1: Xg[t][n][b] = sum_k Wx4[n][k]*X[b][t][k] + bias[n], bf16 out
// Grid: (512 timesteps, 64 n-tiles), block 256 = 4 waves, tile 64(n) x 64(b)
__global__ __launch_bounds__(256) void k_xgemm(const unsigned short* __restrict__ Wx,
                                               const unsigned short* __restrict__ Xb,
                                               const float* __restrict__ bias,
                                               unsigned short* __restrict__ Xg) {
    const int T  = blockIdx.x;
    const int n0 = blockIdx.y * 64;
    __shared__ unsigned short At[64 * 40];   // 64 rows x 32 k, padded stride 40 (bank-safe)
    __shared__ unsigned short Bt[64 * 40];
    const int tid = threadIdx.x;
    const int w   = tid >> 6;
    const int l   = tid & 63;
    const int l15 = l & 15, lq = l >> 4;
    const int sr  = tid >> 2, ss = tid & 3;  // staging: row, 8-elem segment

    f32x4 acc[4] = {{0.f,0.f,0.f,0.f},{0.f,0.f,0.f,0.f},{0.f,0.f,0.f,0.f},{0.f,0.f,0.f,0.f}};

    for (int k0 = 0; k0 < 1024; k0 += 32) {
        __syncthreads();
        *(uint4*)(&At[sr * 40 + ss * 8]) = *(const uint4*)(&Wx[(n0 + sr) * 1024 + k0 + ss * 8]);
        *(uint4*)(&Bt[sr * 40 + ss * 8]) = *(const uint4*)(&Xb[((size_t)(sr * 512 + T)) * 1024 + k0 + ss * 8]);
        __syncthreads();
        short8 a = *(const short8*)(&At[(w * 16 + l15) * 40 + lq * 8]);
#pragma unroll
        for (int j = 0; j < 4; ++j) {
            short8 b = *(const short8*)(&Bt[(j * 16 + l15) * 40 + lq * 8]);
            acc[j] = __builtin_amdgcn_mfma_f32_16x16x32_bf16(a, b, acc[j], 0, 0, 0);
        }
    }
#pragma unroll
    for (int rr = 0; rr < 4; ++rr) {
        int n = n0 + w * 16 + lq * 4 + rr;
        float bs = bias[n];
#pragma unroll
        for (int j = 0; j < 4; ++j) {
            int b = j * 16 + l15;
            Xg[((size_t)T * 4096 + n) * 64 + b] = f2bf(acc[j][rr] + bs);
        }
    }
}

// --- phase 2: persistent cooperative recurrence.
// 256 blocks: ib=blk&63 (16 hidden units), jb=blk>>6 (16 batches). Wave = gate.
// A-frags (Wh slice, 16 rows x 1024 K) live in 128 VGPRs for all 512 steps.
__global__ __launch_bounds__(256, 1) void k_rec(const unsigned short* __restrict__ Wh,
                                                const unsigned short* __restrict__ Xg,
                                                const float* __restrict__ c0,
                                                unsigned short* __restrict__ h0buf,
                                                unsigned short* __restrict__ h1buf) {
    const int blk = blockIdx.x;
    const int ib = blk & 63;
    const int jb = blk >> 6;
    const int tid = threadIdx.x;
    const int g   = tid >> 6;      // wave index = gate (i,f,o,g)
    const int l   = tid & 63;
    const int l15 = l & 15, lq = l >> 4;

    __shared__ unsigned short hTl[16 * 1032];   // 16 batches x 1024 k, padded stride 1032
    __shared__ float P[4][16][16];              // [gate][hid][batch] preactivations

    // Preload persistent A-fragments (Wh rows for this wave's gate + hidden tile)
    short8 afrag[32];
    {
        const unsigned short* wrow = Wh + ((size_t)(g * 1024 + ib * 16 + l15)) * 1024;
#pragma unroll
        for (int ks = 0; ks < 32; ++ks)
            afrag[ks] = *(const short8*)(wrow + ks * 32 + lq * 8);
    }

    const int hid_loc = tid & 15, b_loc = tid >> 4;   // update-phase mapping
    float c = c0[ib * 16 + hid_loc];

    cg::grid_group grid = cg::this_grid();

    for (int t = 0; t < SEQL; ++t) {
        const unsigned short* hsrc = (t & 1) ? h1buf : h0buf;
        unsigned short* hdst = (t & 1) ? h0buf : h1buf;

        // early independent loads: this lane's Xg values for step t
        float xg[4];
#pragma unroll
        for (int rr = 0; rr < 4; ++rr) {
            int n = g * 1024 + ib * 16 + lq * 4 + rr;
            xg[rr] = bf2f(Xg[((size_t)t * 4096 + n) * 64 + jb * 16 + l15]);
        }

        // stage h slice (16 batches x 1024) into LDS
        {
            int rr = tid >> 4, ln = tid & 15;
#pragma unroll
            for (int p = 0; p < 8; ++p) {
                int ko = p * 128 + ln * 8;
                *(uint4*)(&hTl[rr * 1032 + ko]) = *(const uint4*)(&hsrc[(jb * 16 + rr) * 1024 + ko]);
            }
        }
        __syncthreads();

        f32x4 acc = {0.f, 0.f, 0.f, 0.f};
#pragma unroll
        for (int ks = 0; ks < 32; ++ks) {
            short8 b = *(const short8*)(&hTl[l15 * 1032 + ks * 32 + lq * 8]);
            acc = __builtin_amdgcn_mfma_f32_16x16x32_bf16(afrag[ks], b, acc, 0, 0, 0);
        }

#pragma unroll
        for (int rr = 0; rr < 4; ++rr)
            P[g][lq * 4 + rr][l15] = acc[rr] + xg[rr];
        __syncthreads();

        // gate math + state update (c stays in this thread's register)
        {
            float pi = P[0][hid_loc][b_loc];
            float pf = P[1][hid_loc][b_loc];
            float po = P[2][hid_loc][b_loc];
            float pg = P[3][hid_loc][b_loc];
            float ig = sigmoidf_fast(pi);
            float fg = sigmoidf_fast(pf);
            float og = sigmoidf_fast(po);
            float gg = tanhf_fast(pg);
            c = fg * c + ig * gg;
            float hh = og * tanhf_fast(c);
            hdst[(jb * 16 + b_loc) * 1024 + ib * 16 + hid_loc] = f2bf(hh);
        }
        grid.sync();
    }
    // 512 steps: final h landed in h0buf (last write at t=511 -> hdst=h0buf)
}

// --- output: out[b][o] = sum_k h[b][k] * w[o][k], via wT[k][o] for coalescing
__global__ __launch_bounds__(256) void k_out(const unsigned short* __restrict__ hT,
                                             const float* __restrict__ wT,
                                             float* __restrict__ out) {
    const int b = blockIdx.x;
    const int tid = threadIdx.x;
    __shared__ float hs[1024];
#pragma unroll
    for (int p = 0; p < 4; ++p)
        hs[p * 256 + tid] = bf2f(hT[b * 1024 + p * 256 + tid]);
    __syncthreads();
    float a0 = 0.f, a1 = 0.f;
    for (int k = 0; k < 1024; ++k) {
        float hv = hs[k];
        a0 = fmaf(hv, wT[k * 512 + tid], a0);
        a1 = fmaf(hv, wT[k * 512 + 256 + tid], a1);
    }
    out[b * 512 + tid] = a0;
    out[b * 512 + 256 + tid] = a1;
}

extern "C" void kernel_launch(void* const* d_in, const int* in_sizes, int n_in,
                              void* d_out, int out_size, void* d_ws, size_t ws_size,
                              hipStream_t stream) {
    const float* X    = (const float*)d_in[0];
    const float* c0   = (const float*)d_in[1];
    const float* h0   = (const float*)d_in[2];
    const float* w_hi = (const float*)d_in[3];
    const float* w_xi = (const float*)d_in[4];
    const float* b_hi = (const float*)d_in[5];
    const float* b_xi = (const float*)d_in[6];
    const float* w_hf = (const float*)d_in[7];
    const float* w_xf = (const float*)d_in[8];
    const float* b_hf = (const float*)d_in[9];
    const float* b_xf = (const float*)d_in[10];
    const float* w_ho = (const float*)d_in[11];
    const float* w_xo = (const float*)d_in[12];
    const float* b_ho = (const float*)d_in[13];
    const float* b_xo = (const float*)d_in[14];
    const float* w_hg = (const float*)d_in[15];
    const float* w_xg = (const float*)d_in[16];
    const float* b_hg = (const float*)d_in[17];
    const float* b_xg = (const float*)d_in[18];
    const float* w    = (const float*)d_in[19];

    // workspace layout (all 16B-aligned); total = 354,697,216 B (~338 MiB)
    char* ws = (char*)d_ws;
    size_t off = 0;
    unsigned short* Xg  = (unsigned short*)(ws + off); off += (size_t)512 * 4096 * 64 * 2;  // 268435456
    unsigned short* Whp = (unsigned short*)(ws + off); off += (size_t)4096 * 1024 * 2;      // 8388608
    unsigned short* Wxp = (unsigned short*)(ws + off); off += (size_t)4096 * 1024 * 2;      // 8388608
    unsigned short* Xb  = (unsigned short*)(ws + off); off += (size_t)64 * 512 * 1024 * 2;  // 67108864
    float*          bias= (float*)(ws + off);          off += (size_t)4096 * 4;             // 16384
    float*          wT  = (float*)(ws + off);          off += (size_t)1024 * 512 * 4;       // 2097152
    unsigned short* hT0 = (unsigned short*)(ws + off); off += (size_t)64 * 1024 * 2;        // 131072
    unsigned short* hT1 = (unsigned short*)(ws + off); off += (size_t)64 * 1024 * 2;        // 131072
    if (ws_size < off) return;  // fail loudly (out stays zero) -> signals ws too small

    k_pack_w<<<4096, 256, 0, stream>>>(w_hi, w_hf, w_ho, w_hg, Whp);
    k_pack_w<<<4096, 256, 0, stream>>>(w_xi, w_xf, w_xo, w_xg, Wxp);
    k_misc<<<(4096 + 65536 + 524288 + 255) / 256, 256, 0, stream>>>(
        b_hi, b_xi, b_hf, b_xf, b_ho, b_xo, b_hg, b_xg, h0, w, bias, hT0, wT);
    k_convert_x<<<33554432 / 4 / 256, 256, 0, stream>>>(X, Xb);

    k_xgemm<<<dim3(512, 64), 256, 0, stream>>>(Wxp, Xb, bias, Xg);

    void* args[] = {(void*)&Whp, (void*)&Xg, (void*)&c0, (void*)&hT0, (void*)&hT1};
    hipLaunchCooperativeKernel((void*)k_rec, dim3(256), dim3(256), args, 0, stream);

    k_out<<<64, 256, 0, stream>>>(hT0, wT, (float*)d_out);
}

// Round 2
// 3046.733 us; speedup vs baseline: 5.9198x; 5.9198x over previous
//
#include <hip/hip_runtime.h>

// ---------------------------------------------------------------------------
// LSTM: B=64, SEQ=512, I=1024, H=1024, O=512, fp32 in/out.
//   prep:   pack Wh4/Wx4 -> bf16 [4096][1024], bias[n]=b_h+b_x, X->bf16,
//           hT0[b][k] = h0[k] (bf16), wT[k][o] = w[o][k] (fp32)
//   phase1: Xg[t][n][b] = X[b,t,:] . Wx4[n,:] + bias[n]   (bf16 MFMA GEMM)
//   phase2: cooperative persistent kernel, 512 steps, Wh A-frags resident,
//           h slice staged in LDS, c in thread registers.
//           R2 change: custom relaxed-atomic barrier per batch-group (4 groups
//           of 64 blocks) instead of cg::grid.sync(). All cross-block data
//           (h buffers, counters) moves via agent-scope relaxed atomics
//           (sc0/sc1 -> L3-coherent, no L2 writeback/invalidate), release
//           ordering by explicit s_waitcnt vmcnt(0) before arrival.
//   out:    out[b][o] = h[b,:] . w[o,:]
// ---------------------------------------------------------------------------

typedef short short8 __attribute__((ext_vector_type(8)));   // 8 bf16
typedef float f32x4 __attribute__((ext_vector_type(4)));

#define HID   1024
#define G4    4096
#define NBAT  64
#define SEQL  512
#define OUTD  512

// Barrier counters: one per batch-group (jb=0..3), 128 B apart.
// Device global (not ws) so ws layout is untouched; re-zeroed by k_misc
// every call (harness requires identical work per call - satisfied).
__device__ unsigned g_bars[128];

__device__ __forceinline__ unsigned short f2bf(float f) {
    unsigned int u = __builtin_bit_cast(unsigned int, f);
    u += 0x7FFFu + ((u >> 16) & 1u);            // round-to-nearest-even
    return (unsigned short)(u >> 16);
}
__device__ __forceinline__ float bf2f(unsigned short s) {
    unsigned int u = ((unsigned int)s) << 16;
    return __builtin_bit_cast(float, u);
}
__device__ __forceinline__ float sigmoidf_fast(float x) {
    return 1.f / (1.f + __expf(-x));
}
__device__ __forceinline__ float tanhf_fast(float x) {
    return 1.f - 2.f / (1.f + __expf(2.f * x));
}

// --- prep: pack 4 gate weight matrices (fp32 [1024][1024] each) into bf16 [4096][1024]
__global__ void k_pack_w(const float* __restrict__ w0, const float* __restrict__ w1,
                         const float* __restrict__ w2, const float* __restrict__ w3,
                         unsigned short* __restrict__ dst) {
    int idx4 = blockIdx.x * blockDim.x + threadIdx.x;   // over 4096*1024/4 = 1048576
    int n  = idx4 >> 8;            // row 0..4095  (256 float4 per row)
    int k4 = (idx4 & 255) * 4;
    int g = n >> 10, r = n & 1023;
    const float* src = (g == 0) ? w0 : (g == 1) ? w1 : (g == 2) ? w2 : w3;
    float4 v = *(const float4*)(src + r * 1024 + k4);
    ushort4 o;
    o.x = f2bf(v.x); o.y = f2bf(v.y); o.z = f2bf(v.z); o.w = f2bf(v.w);
    *(ushort4*)(dst + n * 1024 + k4) = o;
}

// --- prep: bias[4096], hT0 (bf16 [64][1024] = h0 broadcast), wT (fp32 [1024][512]),
//           zero barrier counters
__global__ void k_misc(const float* __restrict__ b_hi, const float* __restrict__ b_xi,
                       const float* __restrict__ b_hf, const float* __restrict__ b_xf,
                       const float* __restrict__ b_ho, const float* __restrict__ b_xo,
                       const float* __restrict__ b_hg, const float* __restrict__ b_xg,
                       const float* __restrict__ h0, const float* __restrict__ w,
                       float* __restrict__ bias, unsigned short* __restrict__ hT0,
                       float* __restrict__ wT) {
    int idx = blockIdx.x * blockDim.x + threadIdx.x;
    if (idx < 4096) {
        int g = idx >> 10, r = idx & 1023;
        const float* bh = (g == 0) ? b_hi : (g == 1) ? b_hf : (g == 2) ? b_ho : b_hg;
        const float* bx = (g == 0) ? b_xi : (g == 1) ? b_xf : (g == 2) ? b_xo : b_xg;
        bias[idx] = bh[r] + bx[r];
    } else if (idx < 4096 + 65536) {
        int e = idx - 4096;
        int k = e & 1023;
        hT0[e] = f2bf(h0[k]);
    } else if (idx < 4096 + 65536 + 524288) {
        int e = idx - 69632;
        int k = e >> 9, o = e & 511;
        wT[e] = w[o * 1024 + k];
    } else if (idx < 4096 + 65536 + 524288 + 128) {
        int e = idx - (4096 + 65536 + 524288);
        __hip_atomic_store(&g_bars[e], 0u, __ATOMIC_RELAXED, __HIP_MEMORY_SCOPE_AGENT);
    }
}

// --- prep: X fp32 -> bf16, same (b,t,k) layout
__global__ void k_convert_x(const float* __restrict__ X, unsigned short* __restrict__ Xb) {
    int idx = blockIdx.x * blockDim.x + threadIdx.x;    // over 33554432/4
    float4 v = ((const float4*)X)[idx];
    ushort4 o;
    o.x = f2bf(v.x); o.y = f2bf(v.y); o.z = f2bf(v.z); o.w = f2bf(v.w);
    ((ushort4*)Xb)[idx] = o;
}

// --- phase 1: Xg[t][n][b] = sum_k Wx4[n][k]*X[b][t][k] + bias[n], bf16 out
__global__ __launch_bounds__(256) void k_xgemm(const unsigned short* __restrict__ Wx,
                                               const unsigned short* __restrict__ Xb,
                                               const float* __restrict__ bias,
                                               unsigned short* __restrict__ Xg) {
    const int T  = blockIdx.x;
    const int n0 = blockIdx.y * 64;
    __shared__ unsigned short At[64 * 40];
    __shared__ unsigned short Bt[64 * 40];
    const int tid = threadIdx.x;
    const int w   = tid >> 6;
    const int l   = tid & 63;
    const int l15 = l & 15, lq = l >> 4;
    const int sr  = tid >> 2, ss = tid & 3;

    f32x4 acc[4] = {{0.f,0.f,0.f,0.f},{0.f,0.f,0.f,0.f},{0.f,0.f,0.f,0.f},{0.f,0.f,0.f,0.f}};

    for (int k0 = 0; k0 < 1024; k0 += 32) {
        __syncthreads();
        *(uint4*)(&At[sr * 40 + ss * 8]) = *(const uint4*)(&Wx[(n0 + sr) * 1024 + k0 + ss * 8]);
        *(uint4*)(&Bt[sr * 40 + ss * 8]) = *(const uint4*)(&Xb[((size_t)(sr * 512 + T)) * 1024 + k0 + ss * 8]);
        __syncthreads();
        short8 a = *(const short8*)(&At[(w * 16 + l15) * 40 + lq * 8]);
#pragma unroll
        for (int j = 0; j < 4; ++j) {
            short8 b = *(const short8*)(&Bt[(j * 16 + l15) * 40 + lq * 8]);
            acc[j] = __builtin_amdgcn_mfma_f32_16x16x32_bf16(a, b, acc[j], 0, 0, 0);
        }
    }
#pragma unroll
    for (int rr = 0; rr < 4; ++rr) {
        int n = n0 + w * 16 + lq * 4 + rr;
        float bs = bias[n];
#pragma unroll
        for (int j = 0; j < 4; ++j) {
            int b = j * 16 + l15;
            Xg[((size_t)T * 4096 + n) * 64 + b] = f2bf(acc[j][rr] + bs);
        }
    }
}

// --- phase 2: persistent recurrence with custom per-group barrier.
// 256 blocks: ib=blk&63 (16 hidden units), jb=blk>>6 (16 batches). Wave = gate.
__global__ __launch_bounds__(256, 1) void k_rec(const unsigned short* __restrict__ Wh,
                                                const unsigned short* __restrict__ Xg,
                                                const float* __restrict__ c0,
                                                unsigned short* __restrict__ h0buf,
                                                unsigned short* __restrict__ h1buf) {
    const int blk = blockIdx.x;
    const int ib = blk & 63;
    const int jb = blk >> 6;
    const int tid = threadIdx.x;
    const int g   = tid >> 6;      // wave index = gate (i,f,o,g)
    const int l   = tid & 63;
    const int l15 = l & 15, lq = l >> 4;

    __shared__ unsigned short hTl[16 * 1032];   // 16 batches x 1024 k, stride 1032
    __shared__ float P[4][16][16];              // [gate][hid][batch]

    // Persistent A-fragments (Wh rows for this wave's gate + hidden tile)
    short8 afrag[32];
    {
        const unsigned short* wrow = Wh + ((size_t)(g * 1024 + ib * 16 + l15)) * 1024;
#pragma unroll
        for (int ks = 0; ks < 32; ++ks)
            afrag[ks] = *(const short8*)(wrow + ks * 32 + lq * 8);
    }

    const int hid_loc = tid & 15, b_loc = tid >> 4;
    float c = c0[ib * 16 + hid_loc];

    unsigned* bar = &g_bars[jb * 32];           // per-batch-group counter, 128 B apart
    const int srow = tid >> 4, sln = tid & 15;  // staging: row (batch), lane-in-row

    for (int t = 0; t < SEQL; ++t) {
        const unsigned short* hsrc = (t & 1) ? h1buf : h0buf;
        unsigned short* hdst = (t & 1) ? h0buf : h1buf;

        // early independent loads: this lane's Xg values for step t
        float xg[4];
#pragma unroll
        for (int rr = 0; rr < 4; ++rr) {
            int n = g * 1024 + ib * 16 + lq * 4 + rr;
            xg[rr] = bf2f(Xg[((size_t)t * 4096 + n) * 64 + jb * 16 + l15]);
        }

        // stage h slice (16 batches x 1024 k) into LDS via L3-coherent loads
        {
            const unsigned long long* hs64 =
                (const unsigned long long*)hsrc + (size_t)(jb * 16 + srow) * 256;
            unsigned long long tmp[16];
#pragma unroll
            for (int p = 0; p < 16; ++p)
                tmp[p] = __hip_atomic_load(hs64 + p * 16 + sln,
                                           __ATOMIC_RELAXED, __HIP_MEMORY_SCOPE_AGENT);
#pragma unroll
            for (int p = 0; p < 16; ++p)
                *(unsigned long long*)(&hTl[srow * 1032 + (p * 16 + sln) * 4]) = tmp[p];
        }
        __syncthreads();

        f32x4 acc = {0.f, 0.f, 0.f, 0.f};
#pragma unroll
        for (int ks = 0; ks < 32; ++ks) {
            short8 b = *(const short8*)(&hTl[l15 * 1032 + ks * 32 + lq * 8]);
            acc = __builtin_amdgcn_mfma_f32_16x16x32_bf16(afrag[ks], b, acc, 0, 0, 0);
        }

#pragma unroll
        for (int rr = 0; rr < 4; ++rr)
            P[g][lq * 4 + rr][l15] = acc[rr] + xg[rr];
        __syncthreads();

        // gate math + state update; h written via L3-coherent u32 stores
        {
            float pi = P[0][hid_loc][b_loc];
            float pf = P[1][hid_loc][b_loc];
            float po = P[2][hid_loc][b_loc];
            float pg = P[3][hid_loc][b_loc];
            float ig = sigmoidf_fast(pi);
            float fg = sigmoidf_fast(pf);
            float og = sigmoidf_fast(po);
            float gg = tanhf_fast(pg);
            c = fg * c + ig * gg;
            float hh = og * tanhf_fast(c);
            unsigned hb = (unsigned)f2bf(hh);
            unsigned other = __shfl_xor(hb, 1);     // partner hid_loc^1 == tid^1
            if ((tid & 1) == 0) {
                unsigned v = hb | (other << 16);    // lo = even hid, hi = odd hid
                unsigned eidx = ((jb * 16 + b_loc) * 1024 + ib * 16 + hid_loc) >> 1;
                __hip_atomic_store((unsigned*)hdst + eidx, v,
                                   __ATOMIC_RELAXED, __HIP_MEMORY_SCOPE_AGENT);
            }
        }

        // --- custom barrier (64 blocks sharing jb) ---
        // hand-made release: drain sc1 stores to the coherence point (L3),
        // then relaxed arrival; readers' sc1 loads need no acquire-invalidate.
        asm volatile("s_waitcnt vmcnt(0)" ::: "memory");
        __syncthreads();
        if (tid == 0) {
            unsigned tgt = 64u * (unsigned)(t + 1);
            __hip_atomic_fetch_add(bar, 1u, __ATOMIC_RELAXED, __HIP_MEMORY_SCOPE_AGENT);
            while (__hip_atomic_load(bar, __ATOMIC_RELAXED, __HIP_MEMORY_SCOPE_AGENT) < tgt)
                __builtin_amdgcn_s_sleep(1);
        }
        __syncthreads();
    }
    // final h (t=511 odd -> hdst=h0buf) is in h0buf
}

// --- output: out[b][o] = sum_k h[b][k] * w[o][k]
__global__ __launch_bounds__(256) void k_out(const unsigned short* __restrict__ hT,
                                             const float* __restrict__ wT,
                                             float* __restrict__ out) {
    const int b = blockIdx.x;
    const int tid = threadIdx.x;
    __shared__ float hs[1024];
#pragma unroll
    for (int p = 0; p < 4; ++p)
        hs[p * 256 + tid] = bf2f(hT[b * 1024 + p * 256 + tid]);
    __syncthreads();
    float a0 = 0.f, a1 = 0.f;
    for (int k = 0; k < 1024; ++k) {
        float hv = hs[k];
        a0 = fmaf(hv, wT[k * 512 + tid], a0);
        a1 = fmaf(hv, wT[k * 512 + 256 + tid], a1);
    }
    out[b * 512 + tid] = a0;
    out[b * 512 + 256 + tid] = a1;
}

extern "C" void kernel_launch(void* const* d_in, const int* in_sizes, int n_in,
                              void* d_out, int out_size, void* d_ws, size_t ws_size,
                              hipStream_t stream) {
    const float* X    = (const float*)d_in[0];
    const float* c0   = (const float*)d_in[1];
    const float* h0   = (const float*)d_in[2];
    const float* w_hi = (const float*)d_in[3];
    const float* w_xi = (const float*)d_in[4];
    const float* b_hi = (const float*)d_in[5];
    const float* b_xi = (const float*)d_in[6];
    const float* w_hf = (const float*)d_in[7];
    const float* w_xf = (const float*)d_in[8];
    const float* b_hf = (const float*)d_in[9];
    const float* b_xf = (const float*)d_in[10];
    const float* w_ho = (const float*)d_in[11];
    const float* w_xo = (const float*)d_in[12];
    const float* b_ho = (const float*)d_in[13];
    const float* b_xo = (const float*)d_in[14];
    const float* w_hg = (const float*)d_in[15];
    const float* w_xg = (const float*)d_in[16];
    const float* b_hg = (const float*)d_in[17];
    const float* b_xg = (const float*)d_in[18];
    const float* w    = (const float*)d_in[19];

    // workspace layout (all 16B-aligned); total = 354,697,216 B (~338 MiB)
    char* ws = (char*)d_ws;
    size_t off = 0;
    unsigned short* Xg  = (unsigned short*)(ws + off); off += (size_t)512 * 4096 * 64 * 2;
    unsigned short* Whp = (unsigned short*)(ws + off); off += (size_t)4096 * 1024 * 2;
    unsigned short* Wxp = (unsigned short*)(ws + off); off += (size_t)4096 * 1024 * 2;
    unsigned short* Xb  = (unsigned short*)(ws + off); off += (size_t)64 * 512 * 1024 * 2;
    float*          bias= (float*)(ws + off);          off += (size_t)4096 * 4;
    float*          wT  = (float*)(ws + off);          off += (size_t)1024 * 512 * 4;
    unsigned short* hT0 = (unsigned short*)(ws + off); off += (size_t)64 * 1024 * 2;
    unsigned short* hT1 = (unsigned short*)(ws + off); off += (size_t)64 * 1024 * 2;
    if (ws_size < off) return;

    k_pack_w<<<4096, 256, 0, stream>>>(w_hi, w_hf, w_ho, w_hg, Whp);
    k_pack_w<<<4096, 256, 0, stream>>>(w_xi, w_xf, w_xo, w_xg, Wxp);
    k_misc<<<(4096 + 65536 + 524288 + 128 + 255) / 256, 256, 0, stream>>>(
        b_hi, b_xi, b_hf, b_xf, b_ho, b_xo, b_hg, b_xg, h0, w, bias, hT0, wT);
    k_convert_x<<<33554432 / 4 / 256, 256, 0, stream>>>(X, Xb);

    k_xgemm<<<dim3(512, 64), 256, 0, stream>>>(Wxp, Xb, bias, Xg);

    void* args[] = {(void*)&Whp, (void*)&Xg, (void*)&c0, (void*)&hT0, (void*)&hT1};
    hipLaunchCooperativeKernel((void*)k_rec, dim3(256), dim3(256), args, 0, stream);

    k_out<<<64, 256, 0, stream>>>(hT0, wT, (float*)d_out);
}

// Round 3
// 2488.086 us; speedup vs baseline: 7.2490x; 1.2245x over previous
//
#include <hip/hip_runtime.h>

// ---------------------------------------------------------------------------
// LSTM: B=64, SEQ=512, I=1024, H=1024, O=512, fp32 in/out.
//   prep:   pack Wh4/Wx4 -> bf16 [4096][1024], bias[n]=b_h+b_x, X->bf16,
//           hT0[b][k] = h0[k] (bf16), wT[k][o] = w[o][k] (fp32)
//   phase1: Xg[t][n][b] = X[b,t,:] . Wx4[n,:] + bias[n]
//           R3: 128x128 tile + global_load_lds width16 (m97 structure)
//   phase2: persistent recurrence.
//           R3: 128 blocks x 512 thr (8 waves = 4 gates x 2 hid subtiles),
//           afrag pinned in VGPRs via opaque asm (R2's VGPR_Count=92 proved
//           the compiler was re-loading 8MB of Wh from L2 every step),
//           flag-array barrier (32 parallel flag stores + one vector-load
//           poll, no serialized fetch-add), next-step Xg prefetch.
//   out:    out[b][o] = h[b,:] . w[o,:]
// ---------------------------------------------------------------------------

typedef short short8 __attribute__((ext_vector_type(8)));   // 8 bf16
typedef float f32x4 __attribute__((ext_vector_type(4)));

typedef __attribute__((address_space(1))) const unsigned int glb_u32;
typedef __attribute__((address_space(3))) unsigned int lds_u32;

#define SEQL  512

// Barrier flags: [group jb 0..3][block-in-group 0..31], one 128B line/group.
__device__ __attribute__((aligned(128))) unsigned g_bars[128];

__device__ __forceinline__ unsigned short f2bf(float f) {
    unsigned int u = __builtin_bit_cast(unsigned int, f);
    u += 0x7FFFu + ((u >> 16) & 1u);            // round-to-nearest-even
    return (unsigned short)(u >> 16);
}
__device__ __forceinline__ float bf2f(unsigned short s) {
    unsigned int u = ((unsigned int)s) << 16;
    return __builtin_bit_cast(float, u);
}
__device__ __forceinline__ float sigmoidf_fast(float x) {
    return 1.f / (1.f + __expf(-x));
}
__device__ __forceinline__ float tanhf_fast(float x) {
    return 1.f - 2.f / (1.f + __expf(2.f * x));
}
__device__ __forceinline__ void gld_lds16(const unsigned short* g, unsigned short* l) {
    __builtin_amdgcn_global_load_lds((glb_u32*)g, (lds_u32*)l, 16, 0, 0);
}

// --- prep: pack 4 gate weight matrices (fp32 [1024][1024] each) into bf16 [4096][1024]
__global__ void k_pack_w(const float* __restrict__ w0, const float* __restrict__ w1,
                         const float* __restrict__ w2, const float* __restrict__ w3,
                         unsigned short* __restrict__ dst) {
    int idx4 = blockIdx.x * blockDim.x + threadIdx.x;   // over 4096*1024/4
    int n  = idx4 >> 8;
    int k4 = (idx4 & 255) * 4;
    int g = n >> 10, r = n & 1023;
    const float* src = (g == 0) ? w0 : (g == 1) ? w1 : (g == 2) ? w2 : w3;
    float4 v = *(const float4*)(src + r * 1024 + k4);
    ushort4 o;
    o.x = f2bf(v.x); o.y = f2bf(v.y); o.z = f2bf(v.z); o.w = f2bf(v.w);
    *(ushort4*)(dst + n * 1024 + k4) = o;
}

// --- prep: bias[4096], hT0 (bf16 [64][1024] = h0 broadcast), wT (fp32 [1024][512]),
//           zero barrier flags
__global__ void k_misc(const float* __restrict__ b_hi, const float* __restrict__ b_xi,
                       const float* __restrict__ b_hf, const float* __restrict__ b_xf,
                       const float* __restrict__ b_ho, const float* __restrict__ b_xo,
                       const float* __restrict__ b_hg, const float* __restrict__ b_xg,
                       const float* __restrict__ h0, const float* __restrict__ w,
                       float* __restrict__ bias, unsigned short* __restrict__ hT0,
                       float* __restrict__ wT) {
    int idx = blockIdx.x * blockDim.x + threadIdx.x;
    if (idx < 4096) {
        int g = idx >> 10, r = idx & 1023;
        const float* bh = (g == 0) ? b_hi : (g == 1) ? b_hf : (g == 2) ? b_ho : b_hg;
        const float* bx = (g == 0) ? b_xi : (g == 1) ? b_xf : (g == 2) ? b_xo : b_xg;
        bias[idx] = bh[r] + bx[r];
    } else if (idx < 4096 + 65536) {
        int e = idx - 4096;
        int k = e & 1023;
        hT0[e] = f2bf(h0[k]);
    } else if (idx < 4096 + 65536 + 524288) {
        int e = idx - 69632;
        int k = e >> 9, o = e & 511;
        wT[e] = w[o * 1024 + k];
    } else if (idx < 4096 + 65536 + 524288 + 128) {
        int e = idx - (4096 + 65536 + 524288);
        __hip_atomic_store(&g_bars[e], 0u, __ATOMIC_RELAXED, __HIP_MEMORY_SCOPE_AGENT);
    }
}

// --- prep: X fp32 -> bf16
__global__ void k_convert_x(const float* __restrict__ X, unsigned short* __restrict__ Xb) {
    int idx = blockIdx.x * blockDim.x + threadIdx.x;
    float4 v = ((const float4*)X)[idx];
    ushort4 o;
    o.x = f2bf(v.x); o.y = f2bf(v.y); o.z = f2bf(v.z); o.w = f2bf(v.w);
    ((ushort4*)Xb)[idx] = o;
}

// --- phase 1: Xg[t][n][b] = sum_k Wx4[n][k]*X[b][t][k] + bias[n]
// C[n=4096][tb=32768] GEMM. 128x128 tiles, BK=32, 256 thr (2x2 waves of
// 64x64), global_load_lds width 16 staging (m97 structure).
__global__ __launch_bounds__(256) void k_xgemm(const unsigned short* __restrict__ Wx,
                                               const unsigned short* __restrict__ Xb,
                                               const float* __restrict__ bias,
                                               unsigned short* __restrict__ Xg) {
    const int jt = blockIdx.x;          // tb tile: cols jt*128.. (= t0..t0+1, b 0..63)
    const int n0 = blockIdx.y * 128;
    const int t0 = jt * 2;
    __shared__ unsigned short At[128 * 32];   // row-major, NO pad (global_load_lds order)
    __shared__ unsigned short Bt[128 * 32];
    const int tid = threadIdx.x;
    const int w   = tid >> 6;
    const int l   = tid & 63;
    const int l15 = l & 15, lq = l >> 4;
    const int wm  = w & 1, wn = w >> 1;
    const int seg = l & 3, cr = w * 16 + (l >> 2);   // staging row/col 0..63, k-seg

    // per-lane global source pointers (advance 32 elem per K iter)
    const unsigned short* gA0 = Wx + (size_t)(n0 + cr) * 1024 + seg * 8;
    const unsigned short* gA1 = gA0 + (size_t)64 * 1024;
    const unsigned short* gB0 = Xb + ((size_t)cr * 512 + t0) * 1024 + seg * 8;
    const unsigned short* gB1 = gB0 + 1024;
    // wave-uniform LDS dest chunks (lane writes base + lane*16B)
    unsigned short* lA0 = At + w * 512;
    unsigned short* lA1 = At + 2048 + w * 512;
    unsigned short* lB0 = Bt + w * 512;
    unsigned short* lB1 = Bt + 2048 + w * 512;

    f32x4 acc[4][4];
#pragma unroll
    for (int mi = 0; mi < 4; ++mi)
#pragma unroll
        for (int nj = 0; nj < 4; ++nj)
            acc[mi][nj] = f32x4{0.f, 0.f, 0.f, 0.f};

    for (int kk = 0; kk < 32; ++kk) {
        __syncthreads();
        gld_lds16(gA0, lA0);
        gld_lds16(gA1, lA1);
        gld_lds16(gB0, lB0);
        gld_lds16(gB1, lB1);
        gA0 += 32; gA1 += 32; gB0 += 32; gB1 += 32;
        __syncthreads();
        short8 af[4], bf[4];
#pragma unroll
        for (int mi = 0; mi < 4; ++mi)
            af[mi] = *(const short8*)(At + (wm * 64 + mi * 16 + l15) * 32 + lq * 8);
#pragma unroll
        for (int nj = 0; nj < 4; ++nj)
            bf[nj] = *(const short8*)(Bt + (wn * 64 + nj * 16 + l15) * 32 + lq * 8);
#pragma unroll
        for (int mi = 0; mi < 4; ++mi)
#pragma unroll
            for (int nj = 0; nj < 4; ++nj)
                acc[mi][nj] = __builtin_amdgcn_mfma_f32_16x16x32_bf16(af[mi], bf[nj], acc[mi][nj], 0, 0, 0);
    }

    // epilogue: C row n (hid-gate), col c -> (t,b)
#pragma unroll
    for (int mi = 0; mi < 4; ++mi) {
#pragma unroll
        for (int rr = 0; rr < 4; ++rr) {
            int n = n0 + wm * 64 + mi * 16 + lq * 4 + rr;
            float bs = bias[n];
#pragma unroll
            for (int nj = 0; nj < 4; ++nj) {
                int c = wn * 64 + nj * 16 + l15;
                int t = t0 + (c >> 6);
                int b = c & 63;
                Xg[((size_t)t * 4096 + n) * 64 + b] = f2bf(acc[mi][nj][rr] + bs);
            }
        }
    }
}

// --- phase 2: persistent recurrence.
// 128 blocks x 512 thr: jb=blk&3 (16 batches), ibb=blk>>2 (32 hid).
// Wave w: gate g=w&3, hid-subtile hs=w>>2. afrag pinned in VGPRs.
__global__ __launch_bounds__(512, 2) void k_rec(const unsigned short* __restrict__ Wh,
                                                const unsigned short* __restrict__ Xg,
                                                const float* __restrict__ c0,
                                                unsigned short* __restrict__ h0buf,
                                                unsigned short* __restrict__ h1buf) {
    const int blk = blockIdx.x;
    const int jb  = blk & 3;
    const int ibb = blk >> 2;
    const int tid = threadIdx.x;
    const int w   = tid >> 6;
    const int g   = w & 3;          // gate (i,f,o,g)
    const int hs  = w >> 2;         // hid subtile 0..1
    const int l   = tid & 63;
    const int l15 = l & 15, lq = l >> 4;

    __shared__ unsigned short hTl[16 * 1032];   // 16 batches x 1024 k, stride 1032
    __shared__ float P[4][32][17];              // [gate][hid][batch], padded

    // Persistent A-fragments: Wh rows for (gate g, hid ibb*32+hs*16+l15), all K.
    // Opaque asm pins them in VGPRs (R2: compiler re-loaded from L2 every step).
    short8 afrag[32];
    {
        const unsigned short* wrow =
            Wh + ((size_t)(g * 1024 + ibb * 32 + hs * 16 + l15)) * 1024;
#pragma unroll
        for (int ks = 0; ks < 32; ++ks)
            afrag[ks] = *(const short8*)(wrow + ks * 32 + lq * 8);
#pragma unroll
        for (int ks = 0; ks < 32; ++ks)
            asm volatile("" : "+v"(afrag[ks]));
    }

    const int hid_loc = tid & 31, b_loc = tid >> 5;   // update-phase mapping
    float c = c0[ibb * 32 + hid_loc];

    const int srow = tid >> 5, sln = tid & 31;        // staging: batch row, lane

    // prologue: Xg for t=0 (MFMA lane mapping)
    const size_t xg_base = (size_t)(g * 1024 + ibb * 32 + hs * 16 + lq * 4) * 64 + jb * 16 + l15;
    float xg[4];
#pragma unroll
    for (int rr = 0; rr < 4; ++rr)
        xg[rr] = bf2f(Xg[xg_base + (size_t)rr * 64]);

    for (int t = 0; t < SEQL; ++t) {
        const unsigned short* hsrc = (t & 1) ? h1buf : h0buf;
        unsigned short* hdst = (t & 1) ? h0buf : h1buf;

        // stage h slice (16 batches x 1024 k) into LDS via L3-coherent loads
        {
            const unsigned long long* hs64 =
                (const unsigned long long*)hsrc + (size_t)(jb * 16 + srow) * 256;
            unsigned long long tmp[8];
#pragma unroll
            for (int p = 0; p < 8; ++p)
                tmp[p] = __hip_atomic_load(hs64 + p * 32 + sln,
                                           __ATOMIC_RELAXED, __HIP_MEMORY_SCOPE_AGENT);
#pragma unroll
            for (int p = 0; p < 8; ++p)
                *(unsigned long long*)(&hTl[srow * 1032 + (p * 32 + sln) * 4]) = tmp[p];
        }
        __syncthreads();

        // prefetch next-step Xg while MFMA runs
        float xgn[4];
        {
            size_t tb = (size_t)((t < SEQL - 1) ? t + 1 : t) * 4096 * 64;
#pragma unroll
            for (int rr = 0; rr < 4; ++rr)
                xgn[rr] = bf2f(Xg[tb + xg_base + (size_t)rr * 64]);
        }

        f32x4 acc = {0.f, 0.f, 0.f, 0.f};
#pragma unroll
        for (int ks = 0; ks < 32; ++ks) {
            short8 b = *(const short8*)(&hTl[l15 * 1032 + ks * 32 + lq * 8]);
            acc = __builtin_amdgcn_mfma_f32_16x16x32_bf16(afrag[ks], b, acc, 0, 0, 0);
        }

#pragma unroll
        for (int rr = 0; rr < 4; ++rr)
            P[g][hs * 16 + lq * 4 + rr][l15] = acc[rr] + xg[rr];
        __syncthreads();

        // gate math + state update; h written via L3-coherent u32 stores
        {
            float pi = P[0][hid_loc][b_loc];
            float pf = P[1][hid_loc][b_loc];
            float po = P[2][hid_loc][b_loc];
            float pg = P[3][hid_loc][b_loc];
            float ig = sigmoidf_fast(pi);
            float fg = sigmoidf_fast(pf);
            float og = sigmoidf_fast(po);
            float gg = tanhf_fast(pg);
            c = fg * c + ig * gg;
            float hh = og * tanhf_fast(c);
            unsigned hb = (unsigned)f2bf(hh);
            unsigned other = __shfl_xor(hb, 1);     // partner hid_loc^1 == tid^1
            if ((tid & 1) == 0) {
                unsigned v = hb | (other << 16);
                unsigned eidx = ((jb * 16 + b_loc) * 1024 + ibb * 32 + hid_loc) >> 1;
                __hip_atomic_store((unsigned*)hdst + eidx, v,
                                   __ATOMIC_RELAXED, __HIP_MEMORY_SCOPE_AGENT);
            }
        }

        // --- flag-array barrier over the 32 blocks sharing jb ---
        asm volatile("s_waitcnt vmcnt(0)" ::: "memory");  // drain own h stores to L3
        __syncthreads();                                   // all waves drained
        if (tid < 64) {
            unsigned tgt = (unsigned)(t + 1);
            if (tid == 0)
                __hip_atomic_store(&g_bars[jb * 32 + ibb], tgt,
                                   __ATOMIC_RELAXED, __HIP_MEMORY_SCOPE_AGENT);
            bool ok;
            do {
                unsigned v = __hip_atomic_load(&g_bars[jb * 32 + (tid & 31)],
                                               __ATOMIC_RELAXED, __HIP_MEMORY_SCOPE_AGENT);
                ok = (tid >= 32) || (v >= tgt);
            } while (!__all(ok));
        }
        __syncthreads();

#pragma unroll
        for (int rr = 0; rr < 4; ++rr) xg[rr] = xgn[rr];
    }
    // t=511 -> hdst = h0buf: final h in h0buf
}

// --- output: out[b][o] = sum_k h[b][k] * w[o][k]
__global__ __launch_bounds__(256) void k_out(const unsigned short* __restrict__ hT,
                                             const float* __restrict__ wT,
                                             float* __restrict__ out) {
    const int b = blockIdx.x;
    const int tid = threadIdx.x;
    __shared__ float hs[1024];
#pragma unroll
    for (int p = 0; p < 4; ++p)
        hs[p * 256 + tid] = bf2f(hT[b * 1024 + p * 256 + tid]);
    __syncthreads();
    float a0 = 0.f, a1 = 0.f;
    for (int k = 0; k < 1024; ++k) {
        float hv = hs[k];
        a0 = fmaf(hv, wT[k * 512 + tid], a0);
        a1 = fmaf(hv, wT[k * 512 + 256 + tid], a1);
    }
    out[b * 512 + tid] = a0;
    out[b * 512 + 256 + tid] = a1;
}

extern "C" void kernel_launch(void* const* d_in, const int* in_sizes, int n_in,
                              void* d_out, int out_size, void* d_ws, size_t ws_size,
                              hipStream_t stream) {
    const float* X    = (const float*)d_in[0];
    const float* c0   = (const float*)d_in[1];
    const float* h0   = (const float*)d_in[2];
    const float* w_hi = (const float*)d_in[3];
    const float* w_xi = (const float*)d_in[4];
    const float* b_hi = (const float*)d_in[5];
    const float* b_xi = (const float*)d_in[6];
    const float* w_hf = (const float*)d_in[7];
    const float* w_xf = (const float*)d_in[8];
    const float* b_hf = (const float*)d_in[9];
    const float* b_xf = (const float*)d_in[10];
    const float* w_ho = (const float*)d_in[11];
    const float* w_xo = (const float*)d_in[12];
    const float* b_ho = (const float*)d_in[13];
    const float* b_xo = (const float*)d_in[14];
    const float* w_hg = (const float*)d_in[15];
    const float* w_xg = (const float*)d_in[16];
    const float* b_hg = (const float*)d_in[17];
    const float* b_xg = (const float*)d_in[18];
    const float* w    = (const float*)d_in[19];

    // workspace layout (all 16B-aligned); total ~338 MiB
    char* ws = (char*)d_ws;
    size_t off = 0;
    unsigned short* Xg  = (unsigned short*)(ws + off); off += (size_t)512 * 4096 * 64 * 2;
    unsigned short* Whp = (unsigned short*)(ws + off); off += (size_t)4096 * 1024 * 2;
    unsigned short* Wxp = (unsigned short*)(ws + off); off += (size_t)4096 * 1024 * 2;
    unsigned short* Xb  = (unsigned short*)(ws + off); off += (size_t)64 * 512 * 1024 * 2;
    float*          bias= (float*)(ws + off);          off += (size_t)4096 * 4;
    float*          wT  = (float*)(ws + off);          off += (size_t)1024 * 512 * 4;
    unsigned short* hT0 = (unsigned short*)(ws + off); off += (size_t)64 * 1024 * 2;
    unsigned short* hT1 = (unsigned short*)(ws + off); off += (size_t)64 * 1024 * 2;
    if (ws_size < off) return;

    k_pack_w<<<4096, 256, 0, stream>>>(w_hi, w_hf, w_ho, w_hg, Whp);
    k_pack_w<<<4096, 256, 0, stream>>>(w_xi, w_xf, w_xo, w_xg, Wxp);
    k_misc<<<(4096 + 65536 + 524288 + 128 + 255) / 256, 256, 0, stream>>>(
        b_hi, b_xi, b_hf, b_xf, b_ho, b_xo, b_hg, b_xg, h0, w, bias, hT0, wT);
    k_convert_x<<<33554432 / 4 / 256, 256, 0, stream>>>(X, Xb);

    k_xgemm<<<dim3(256, 32), 256, 0, stream>>>(Wxp, Xb, bias, Xg);

    void* args[] = {(void*)&Whp, (void*)&Xg, (void*)&c0, (void*)&hT0, (void*)&hT1};
    hipLaunchCooperativeKernel((void*)k_rec, dim3(128), dim3(512), args, 0, stream);

    k_out<<<64, 256, 0, stream>>>(hT0, wT, (float*)d_out);
}